// Round 1
// baseline (299.822 us; speedup 1.0000x reference)
//
#include <hip/hip_runtime.h>
#include <complex>
#include <cmath>

// ---------------- host-side CG table computation (exact port of reference) ----

static double fct(int n) { double r = 1.0; for (int i = 2; i <= n; ++i) r *= i; return r; }

static double su2_cg_coeff(int j1, int m1, int j2, int m2, int j3, int m3) {
    if (m3 != m1 + m2) return 0.0;
    int vmin = std::max(std::max(-j1 + j2 + m3, -j1 + m1), 0);
    int vmax = std::min(std::min(j2 + j3 + m1, j3 - j1 + j2), j3 + m3);
    double C = std::sqrt((2.0 * j3 + 1.0) * fct(j3 + j1 - j2) * fct(j3 - j1 + j2) * fct(j1 + j2 - j3)
                         * fct(j3 + m3) * fct(j3 - m3)
                         / (fct(j1 + j2 + j3 + 1) * fct(j1 - m1) * fct(j1 + m1) * fct(j2 - m2) * fct(j2 + m2)));
    double S = 0.0;
    for (int v = vmin; v <= vmax; ++v) {
        double sgn = ((v + j2 + m2) & 1) ? -1.0 : 1.0;
        S += sgn * fct(j2 + j3 + m1 - v) * fct(j1 - m1 + v)
             / (fct(v) * fct(j3 - j1 + j2 - v) * fct(j3 + m3 - v) * fct(v + j1 - j2 - m3));
    }
    return C * S;
}

// change-of-basis real->complex, rows = complex index (l+m), cols = real index
static void cob(int l, std::complex<double> q[5][5]) {
    for (int a = 0; a < 5; ++a) for (int b = 0; b < 5; ++b) q[a][b] = 0.0;
    const double is2 = 1.0 / std::sqrt(2.0);
    for (int m = -l; m < 0; ++m) {
        q[l + m][l - m] = is2;
        q[l + m][l + m] = std::complex<double>(0.0, -is2);
    }
    q[l][l] = 1.0;
    for (int m = 1; m <= l; ++m) {
        double sgn = (m & 1) ? -1.0 : 1.0;
        q[l + m][l + m] = sgn * is2;
        q[l + m][l - m] = std::complex<double>(0.0, sgn * is2);
    }
    std::complex<double> ph;
    switch (l & 3) {
        case 0: ph = 1.0; break;
        case 1: ph = std::complex<double>(0.0, -1.0); break;
        case 2: ph = -1.0; break;
        default: ph = std::complex<double>(0.0, 1.0); break;
    }
    for (int a = 0; a < 5; ++a) for (int b = 0; b < 5; ++b) q[a][b] *= ph;
}

// real-basis wigner 3j, normalized to unit Frobenius norm. out is d1*d2*d3 row-major [j][l][m].
static void wigner3j(int l1, int l2, int l3, double* out) {
    int d1 = 2 * l1 + 1, d2 = 2 * l2 + 1, d3 = 2 * l3 + 1;
    double csu2[5][5][5] = {};
    for (int m1 = -l1; m1 <= l1; ++m1)
        for (int m2 = -l2; m2 <= l2; ++m2)
            if (std::abs(m1 + m2) <= l3)
                csu2[l1 + m1][l2 + m2][l3 + m1 + m2] =
                    su2_cg_coeff(l1, m1, l2, m2, l3, m1 + m2) / std::sqrt(2.0 * l3 + 1.0);
    std::complex<double> Q1[5][5], Q2[5][5], Q3[5][5];
    cob(l1, Q1); cob(l2, Q2); cob(l3, Q3);
    double nrm = 0.0;
    for (int j = 0; j < d1; ++j)
        for (int l = 0; l < d2; ++l)
            for (int m = 0; m < d3; ++m) {
                std::complex<double> s = 0.0;
                for (int i = 0; i < d1; ++i)
                    for (int k = 0; k < d2; ++k)
                        for (int n = 0; n < d3; ++n)
                            s += Q1[i][j] * Q2[k][l] * std::conj(Q3[n][m]) * csu2[i][k][n];
                out[(j * d2 + l) * d3 + m] = s.real();
                nrm += s.real() * s.real();
            }
    nrm = std::sqrt(nrm);
    for (int t = 0; t < d1 * d2 * d3; ++t) out[t] /= nrm;
}

struct CGTab {
    float cA;        // 0x0->0 scalar coefficient
    float B[9];      // 1x1->0 : [i*3+j]
    float Cjk[9];    // 0x1->1 : [j*3+k]
    float Dik[9];    // 1x0->1 : [i*3+k]
    float E[27];     // 1x1->1 : [(i*3+j)*3+k]
    float F[45];     // 1x1->2 : [(i*3+j)*5+k]
};

// ---------------- device kernel ---------------------------------------------
// R3: nn-vectorized by 4, LDS stage deleted.
// Layout facts (mul1*mul2 == n == 2048), verified against reference reshapes:
//   out[r, c], r = u*32 + v; chunk col = chunk_base + nn*d3 + k3
//   x1_l0[u,nn]   = in1[(u*32 + nn/64)*256 + (nn%64)]
//   x1_l1[i,u,nn] = in1[(f/192)*256 + 64 + f%192],  f = i*131072 + u*2048 + nn
//   x2_l0[v,nn]   = in2[(v*64 + nn/32)*128 + (nn%32)]
//   x2_l1[j,v,nn] = in2[(g/96)*128 + 32 + g%96],    g = j*65536 + v*2048 + nn
// With nn % 4 == 0, every quad is contiguous and 16B-aligned (64/32/192/96 are
// multiples of 4; the /192 and /96 row-wraps land on multiples of 4, so a quad
// never straddles a wrap). -> all loads are float4.
// A thread owning nn..nn+3 owns output floats [base + 3nn .. 3nn+12) (d3=3)
// or [base + 5nn .. 5nn+20) (d3=5): contiguous, 16B-aligned -> direct dwordx4
// stores, no LDS transpose needed. Per-instruction lane stride is 48B/80B; the
// 3 (resp. 5) instructions jointly cover every byte of each 128B line, merged
// in L2 (write-back), so no partial-line penalty.
// One block = one output row r = one contiguous 128KB write stream.
// Sorted chunk float bases within a 32768-float row:
//   A:0  B:2048  C:4096  D:10240  E:16384  F:22528

__global__ __launch_bounds__(256) void ftp_kernel(const float* __restrict__ in1,
                                                  const float* __restrict__ in2,
                                                  float* __restrict__ out,
                                                  CGTab cg) {
    const int t = threadIdx.x;
    const int r = blockIdx.x;            // 0..2047
    const int u = r >> 5;
    const int v = r & 31;
    float* __restrict__ orow = out + (size_t)r * 32768;

#pragma unroll
    for (int h = 0; h < 2; ++h) {
        const int nn = h * 1024 + t * 4;   // quad base, multiple of 4

        alignas(16) float a0q[4], b0q[4], a1q[3][4], b1q[3][4];
        *(float4*)a0q = *(const float4*)&in1[(u * 32 + (nn >> 6)) * 256 + (nn & 63)];
        *(float4*)b0q = *(const float4*)&in2[(v * 64 + (nn >> 5)) * 128 + (nn & 31)];
#pragma unroll
        for (int i = 0; i < 3; ++i) {
            const int f   = i * 131072 + u * 2048 + nn;
            const int row = f / 192, col = f - row * 192;
            *(float4*)a1q[i] = *(const float4*)&in1[row * 256 + 64 + col];
        }
#pragma unroll
        for (int j = 0; j < 3; ++j) {
            const int g   = j * 65536 + v * 2048 + nn;
            const int row = g / 96, col = g - row * 96;
            *(float4*)b1q[j] = *(const float4*)&in2[row * 128 + 32 + col];
        }

        alignas(16) float o[20];

        // ---- A: 0e from 0x0 ----
#pragma unroll
        for (int d = 0; d < 4; ++d) o[d] = cg.cA * a0q[d] * b0q[d];
        *(float4*)&orow[nn] = *(const float4*)o;

        // ---- B: 0e from 1x1 ----
#pragma unroll
        for (int d = 0; d < 4; ++d) {
            float s = 0.f;
#pragma unroll
            for (int i = 0; i < 3; ++i)
#pragma unroll
                for (int j = 0; j < 3; ++j)
                    s = fmaf(cg.B[i * 3 + j], a1q[i][d] * b1q[j][d], s);
            o[d] = s;
        }
        *(float4*)&orow[2048 + nn] = *(const float4*)o;

        // ---- C: 1o from 0x1 ----
#pragma unroll
        for (int d = 0; d < 4; ++d)
#pragma unroll
            for (int k = 0; k < 3; ++k) {
                float s = 0.f;
#pragma unroll
                for (int j = 0; j < 3; ++j) s = fmaf(cg.Cjk[j * 3 + k], b1q[j][d], s);
                o[d * 3 + k] = a0q[d] * s;
            }
#pragma unroll
        for (int s4 = 0; s4 < 3; ++s4)
            *(float4*)&orow[4096 + 3 * nn + 4 * s4] = *(const float4*)&o[4 * s4];

        // ---- D: 1o from 1x0 ----
#pragma unroll
        for (int d = 0; d < 4; ++d)
#pragma unroll
            for (int k = 0; k < 3; ++k) {
                float s = 0.f;
#pragma unroll
                for (int i = 0; i < 3; ++i) s = fmaf(cg.Dik[i * 3 + k], a1q[i][d], s);
                o[d * 3 + k] = b0q[d] * s;
            }
#pragma unroll
        for (int s4 = 0; s4 < 3; ++s4)
            *(float4*)&orow[10240 + 3 * nn + 4 * s4] = *(const float4*)&o[4 * s4];

        // ---- E: 1e from 1x1 ----
#pragma unroll
        for (int d = 0; d < 4; ++d)
#pragma unroll
            for (int k = 0; k < 3; ++k) {
                float s = 0.f;
#pragma unroll
                for (int i = 0; i < 3; ++i)
#pragma unroll
                    for (int j = 0; j < 3; ++j)
                        s = fmaf(cg.E[(i * 3 + j) * 3 + k], a1q[i][d] * b1q[j][d], s);
                o[d * 3 + k] = s;
            }
#pragma unroll
        for (int s4 = 0; s4 < 3; ++s4)
            *(float4*)&orow[16384 + 3 * nn + 4 * s4] = *(const float4*)&o[4 * s4];

        // ---- F: 2e from 1x1 ----
#pragma unroll
        for (int d = 0; d < 4; ++d)
#pragma unroll
            for (int k = 0; k < 5; ++k) {
                float s = 0.f;
#pragma unroll
                for (int i = 0; i < 3; ++i)
#pragma unroll
                    for (int j = 0; j < 3; ++j)
                        s = fmaf(cg.F[(i * 3 + j) * 5 + k], a1q[i][d] * b1q[j][d], s);
                o[d * 5 + k] = s;
            }
#pragma unroll
        for (int s4 = 0; s4 < 5; ++s4)
            *(float4*)&orow[22528 + 5 * nn + 4 * s4] = *(const float4*)&o[4 * s4];
    }
}

// ---------------- launch ------------------------------------------------------

extern "C" void kernel_launch(void* const* d_in, const int* in_sizes, int n_in,
                              void* d_out, int out_size, void* d_ws, size_t ws_size,
                              hipStream_t stream) {
    const float* in1 = (const float*)d_in[0];  // (2048, 256) fp32
    const float* in2 = (const float*)d_in[1];  // (2048, 128) fp32
    float* out = (float*)d_out;                // (2048, 32768) fp32

    // Host-side CG tables (pure CPU math — graph-capture safe; passed by value).
    CGTab cg;
    double w[45];
    const double s3 = std::sqrt(3.0), s5 = std::sqrt(5.0);

    wigner3j(0, 0, 0, w);
    cg.cA = (float)(w[0] * 1.0);

    wigner3j(1, 1, 0, w);  // [i][j][0]
    for (int i = 0; i < 3; ++i)
        for (int j = 0; j < 3; ++j) cg.B[i * 3 + j] = (float)(w[(i * 3 + j)] * 1.0);

    wigner3j(0, 1, 1, w);  // [0][j][k]
    for (int j = 0; j < 3; ++j)
        for (int k = 0; k < 3; ++k) cg.Cjk[j * 3 + k] = (float)(w[j * 3 + k] * s3);

    wigner3j(1, 0, 1, w);  // [i][0][k]
    for (int i = 0; i < 3; ++i)
        for (int k = 0; k < 3; ++k) cg.Dik[i * 3 + k] = (float)(w[i * 3 + k] * s3);

    wigner3j(1, 1, 1, w);  // [i][j][k]
    for (int t = 0; t < 27; ++t) cg.E[t] = (float)(w[t] * s3);

    wigner3j(1, 1, 2, w);  // [i][j][k], d3 = 5
    for (int t = 0; t < 45; ++t) cg.F[t] = (float)(w[t] * s5);

    dim3 grid(2048, 1, 1);
    dim3 block(256, 1, 1);
    ftp_kernel<<<grid, block, 0, stream>>>(in1, in2, out, cg);
}

// Round 2
// 264.428 us; speedup vs baseline: 1.1338x; 1.1338x over previous
//
#include <hip/hip_runtime.h>
#include <complex>
#include <cmath>

// ---------------- host-side CG table computation (exact port of reference) ----

static double fct(int n) { double r = 1.0; for (int i = 2; i <= n; ++i) r *= i; return r; }

static double su2_cg_coeff(int j1, int m1, int j2, int m2, int j3, int m3) {
    if (m3 != m1 + m2) return 0.0;
    int vmin = std::max(std::max(-j1 + j2 + m3, -j1 + m1), 0);
    int vmax = std::min(std::min(j2 + j3 + m1, j3 - j1 + j2), j3 + m3);
    double C = std::sqrt((2.0 * j3 + 1.0) * fct(j3 + j1 - j2) * fct(j3 - j1 + j2) * fct(j1 + j2 - j3)
                         * fct(j3 + m3) * fct(j3 - m3)
                         / (fct(j1 + j2 + j3 + 1) * fct(j1 - m1) * fct(j1 + m1) * fct(j2 - m2) * fct(j2 + m2)));
    double S = 0.0;
    for (int v = vmin; v <= vmax; ++v) {
        double sgn = ((v + j2 + m2) & 1) ? -1.0 : 1.0;
        S += sgn * fct(j2 + j3 + m1 - v) * fct(j1 - m1 + v)
             / (fct(v) * fct(j3 - j1 + j2 - v) * fct(j3 + m3 - v) * fct(v + j1 - j2 - m3));
    }
    return C * S;
}

// change-of-basis real->complex, rows = complex index (l+m), cols = real index
static void cob(int l, std::complex<double> q[5][5]) {
    for (int a = 0; a < 5; ++a) for (int b = 0; b < 5; ++b) q[a][b] = 0.0;
    const double is2 = 1.0 / std::sqrt(2.0);
    for (int m = -l; m < 0; ++m) {
        q[l + m][l - m] = is2;
        q[l + m][l + m] = std::complex<double>(0.0, -is2);
    }
    q[l][l] = 1.0;
    for (int m = 1; m <= l; ++m) {
        double sgn = (m & 1) ? -1.0 : 1.0;
        q[l + m][l + m] = sgn * is2;
        q[l + m][l - m] = std::complex<double>(0.0, sgn * is2);
    }
    std::complex<double> ph;
    switch (l & 3) {
        case 0: ph = 1.0; break;
        case 1: ph = std::complex<double>(0.0, -1.0); break;
        case 2: ph = -1.0; break;
        default: ph = std::complex<double>(0.0, 1.0); break;
    }
    for (int a = 0; a < 5; ++a) for (int b = 0; b < 5; ++b) q[a][b] *= ph;
}

// real-basis wigner 3j, normalized to unit Frobenius norm. out is d1*d2*d3 row-major [j][l][m].
static void wigner3j(int l1, int l2, int l3, double* out) {
    int d1 = 2 * l1 + 1, d2 = 2 * l2 + 1, d3 = 2 * l3 + 1;
    double csu2[5][5][5] = {};
    for (int m1 = -l1; m1 <= l1; ++m1)
        for (int m2 = -l2; m2 <= l2; ++m2)
            if (std::abs(m1 + m2) <= l3)
                csu2[l1 + m1][l2 + m2][l3 + m1 + m2] =
                    su2_cg_coeff(l1, m1, l2, m2, l3, m1 + m2) / std::sqrt(2.0 * l3 + 1.0);
    std::complex<double> Q1[5][5], Q2[5][5], Q3[5][5];
    cob(l1, Q1); cob(l2, Q2); cob(l3, Q3);
    double nrm = 0.0;
    for (int j = 0; j < d1; ++j)
        for (int l = 0; l < d2; ++l)
            for (int m = 0; m < d3; ++m) {
                std::complex<double> s = 0.0;
                for (int i = 0; i < d1; ++i)
                    for (int k = 0; k < d2; ++k)
                        for (int n = 0; n < d3; ++n)
                            s += Q1[i][j] * Q2[k][l] * std::conj(Q3[n][m]) * csu2[i][k][n];
                out[(j * d2 + l) * d3 + m] = s.real();
                nrm += s.real() * s.real();
            }
    nrm = std::sqrt(nrm);
    for (int t = 0; t < d1 * d2 * d3; ++t) out[t] /= nrm;
}

struct CGTab {
    float cA;        // 0x0->0 scalar coefficient
    float B[9];      // 1x1->0 : [i*3+j]
    float Cjk[9];    // 0x1->1 : [j*3+k]
    float Dik[9];    // 1x0->1 : [i*3+k]
    float E[27];     // 1x1->1 : [(i*3+j)*3+k]
    float F[45];     // 1x1->2 : [(i*3+j)*5+k]
};

// ---------------- device kernel ---------------------------------------------
// R4: float4 loads + register compute (from R3) + wave-local LDS transpose so
// EVERY global store is unit-stride across lanes (the R2 property that R3 lost;
// strided dwordx4 stores were a ~4x store-request amplification and the R3
// regression).
//
// Layout facts (mul1*mul2 == n == 2048), verified against reference reshapes:
//   out[r, c], r = u*32 + v; chunk col = chunk_base + nn*d3 + k3
//   x1_l0[u,nn]   = in1[(u*32 + nn/64)*256 + (nn%64)]
//   x1_l1[i,u,nn] = in1[(f/192)*256 + 64 + f%192],  f = i*131072 + u*2048 + nn
//   x2_l0[v,nn]   = in2[(v*64 + nn/32)*128 + (nn%32)]
//   x2_l1[j,v,nn] = in2[(g/96)*128 + 32 + g%96],    g = j*65536 + v*2048 + nn
// With nn % 4 == 0 every operand quad is contiguous + 16B aligned (the /192 and
// /96 row wraps land on multiples of 4) -> all loads are float4.
//
// Wave-local transpose: a wave's 64 quads cover 256 consecutive nn, i.e. a
// contiguous d3*256-float span of each chunk. Thread writes its d3*4 contiguous
// chunk floats to per-wave LDS (lane stride 12 or 20 floats: both cover all 32
// banks per 8 lanes -> conflict-free b128s), then the wave reads back
// unit-stride float4s and stores 1KB-contiguous dwordx4s. DS ops complete
// in-order within a wave -> no __syncthreads anywhere; an explicit
// lgkmcnt(0)+sched_barrier between write and read is the only sync.
// A (d3=1) and B (d3=1) chunks are naturally unit-stride: direct stores.
//
// Sorted chunk bases in float4 units within a row (row = 8192 float4s):
//   A:0  B:512  C:1024  D:2560  E:4096  F:5632

__global__ __launch_bounds__(256) void ftp_kernel(const float* __restrict__ in1,
                                                  const float* __restrict__ in2,
                                                  float* __restrict__ out,
                                                  CGTab cg) {
    __shared__ float lds[4][1280];   // 20 KB: 5 KB wave-local scratch x 4 waves

    const int t    = threadIdx.x;
    const int w    = t >> 6;
    const int lane = t & 63;
    const int r    = blockIdx.x;     // 0..2047
    const int u    = r >> 5;
    const int v    = r & 31;
    float4* __restrict__ orow4 = (float4*)(out + (size_t)r * 32768);
    float* ldsW = lds[w];
    const float4* ldsW4 = (const float4*)ldsW;

    for (int h = 0; h < 2; ++h) {
        const int nn  = h * 1024 + t * 4;            // quad base, multiple of 4
        const int q4w = h * 256 + w * 64;            // wave's nn base / 4

        alignas(16) float a0q[4], b0q[4], a1q[3][4], b1q[3][4];
        *(float4*)a0q = *(const float4*)&in1[(u * 32 + (nn >> 6)) * 256 + (nn & 63)];
        *(float4*)b0q = *(const float4*)&in2[(v * 64 + (nn >> 5)) * 128 + (nn & 31)];
#pragma unroll
        for (int i = 0; i < 3; ++i) {
            const int f   = i * 131072 + u * 2048 + nn;
            const int row = f / 192, col = f - row * 192;
            *(float4*)a1q[i] = *(const float4*)&in1[row * 256 + 64 + col];
        }
#pragma unroll
        for (int j = 0; j < 3; ++j) {
            const int g   = j * 65536 + v * 2048 + nn;
            const int row = g / 96, col = g - row * 96;
            *(float4*)b1q[j] = *(const float4*)&in2[row * 128 + 32 + col];
        }

        // ---- A: 0e from 0x0 (unit-stride, direct) ----
        {
            alignas(16) float o[4];
#pragma unroll
            for (int d = 0; d < 4; ++d) o[d] = cg.cA * a0q[d] * b0q[d];
            orow4[h * 256 + t] = *(const float4*)o;
        }

        // ---- B: 0e from 1x1 (unit-stride, direct) ----
        {
            alignas(16) float o[4];
#pragma unroll
            for (int d = 0; d < 4; ++d) {
                float s = 0.f;
#pragma unroll
                for (int i = 0; i < 3; ++i)
#pragma unroll
                    for (int j = 0; j < 3; ++j)
                        s = fmaf(cg.B[i * 3 + j], a1q[i][d] * b1q[j][d], s);
                o[d] = s;
            }
            orow4[512 + h * 256 + t] = *(const float4*)o;
        }

        alignas(16) float o[20];

        // helper: stage o[0..4*D3) through wave-local LDS, emit D3 coalesced stores
        auto bounce = [&](auto d3c, float4* dst) {
            constexpr int D3 = decltype(d3c)::value;
#pragma unroll
            for (int s = 0; s < D3; ++s)
                *(float4*)&ldsW[lane * 4 * D3 + 4 * s] = *(const float4*)&o[4 * s];
            __builtin_amdgcn_wave_barrier();
            asm volatile("s_waitcnt lgkmcnt(0)" ::: "memory");
            __builtin_amdgcn_sched_barrier(0);
#pragma unroll
            for (int s = 0; s < D3; ++s)
                dst[lane + 64 * s] = ldsW4[lane + 64 * s];
            __builtin_amdgcn_wave_barrier();
        };

        // ---- C: 1o from 0x1 ----
#pragma unroll
        for (int d = 0; d < 4; ++d)
#pragma unroll
            for (int k = 0; k < 3; ++k) {
                float s = 0.f;
#pragma unroll
                for (int j = 0; j < 3; ++j) s = fmaf(cg.Cjk[j * 3 + k], b1q[j][d], s);
                o[d * 3 + k] = a0q[d] * s;
            }
        bounce(std::integral_constant<int, 3>{}, orow4 + 1024 + 3 * q4w);

        // ---- D: 1o from 1x0 ----
#pragma unroll
        for (int d = 0; d < 4; ++d)
#pragma unroll
            for (int k = 0; k < 3; ++k) {
                float s = 0.f;
#pragma unroll
                for (int i = 0; i < 3; ++i) s = fmaf(cg.Dik[i * 3 + k], a1q[i][d], s);
                o[d * 3 + k] = b0q[d] * s;
            }
        bounce(std::integral_constant<int, 3>{}, orow4 + 2560 + 3 * q4w);

        // ---- E: 1e from 1x1 ----
#pragma unroll
        for (int d = 0; d < 4; ++d)
#pragma unroll
            for (int k = 0; k < 3; ++k) {
                float s = 0.f;
#pragma unroll
                for (int i = 0; i < 3; ++i)
#pragma unroll
                    for (int j = 0; j < 3; ++j)
                        s = fmaf(cg.E[(i * 3 + j) * 3 + k], a1q[i][d] * b1q[j][d], s);
                o[d * 3 + k] = s;
            }
        bounce(std::integral_constant<int, 3>{}, orow4 + 4096 + 3 * q4w);

        // ---- F: 2e from 1x1 ----
#pragma unroll
        for (int d = 0; d < 4; ++d)
#pragma unroll
            for (int k = 0; k < 5; ++k) {
                float s = 0.f;
#pragma unroll
                for (int i = 0; i < 3; ++i)
#pragma unroll
                    for (int j = 0; j < 3; ++j)
                        s = fmaf(cg.F[(i * 3 + j) * 5 + k], a1q[i][d] * b1q[j][d], s);
                o[d * 5 + k] = s;
            }
        bounce(std::integral_constant<int, 5>{}, orow4 + 5632 + 5 * q4w);
    }
}

// ---------------- launch ------------------------------------------------------

extern "C" void kernel_launch(void* const* d_in, const int* in_sizes, int n_in,
                              void* d_out, int out_size, void* d_ws, size_t ws_size,
                              hipStream_t stream) {
    const float* in1 = (const float*)d_in[0];  // (2048, 256) fp32
    const float* in2 = (const float*)d_in[1];  // (2048, 128) fp32
    float* out = (float*)d_out;                // (2048, 32768) fp32

    // Host-side CG tables (pure CPU math — graph-capture safe; passed by value).
    CGTab cg;
    double w[45];
    const double s3 = std::sqrt(3.0), s5 = std::sqrt(5.0);

    wigner3j(0, 0, 0, w);
    cg.cA = (float)(w[0] * 1.0);

    wigner3j(1, 1, 0, w);  // [i][j][0]
    for (int i = 0; i < 3; ++i)
        for (int j = 0; j < 3; ++j) cg.B[i * 3 + j] = (float)(w[(i * 3 + j)] * 1.0);

    wigner3j(0, 1, 1, w);  // [0][j][k]
    for (int j = 0; j < 3; ++j)
        for (int k = 0; k < 3; ++k) cg.Cjk[j * 3 + k] = (float)(w[j * 3 + k] * s3);

    wigner3j(1, 0, 1, w);  // [i][0][k]
    for (int i = 0; i < 3; ++i)
        for (int k = 0; k < 3; ++k) cg.Dik[i * 3 + k] = (float)(w[i * 3 + k] * s3);

    wigner3j(1, 1, 1, w);  // [i][j][k]
    for (int t = 0; t < 27; ++t) cg.E[t] = (float)(w[t] * s3);

    wigner3j(1, 1, 2, w);  // [i][j][k], d3 = 5
    for (int t = 0; t < 45; ++t) cg.F[t] = (float)(w[t] * s5);

    dim3 grid(2048, 1, 1);
    dim3 block(256, 1, 1);
    ftp_kernel<<<grid, block, 0, stream>>>(in1, in2, out, cg);
}

// Round 3
// 258.877 us; speedup vs baseline: 1.1582x; 1.0214x over previous
//
#include <hip/hip_runtime.h>
#include <complex>
#include <cmath>

// ---------------- host-side CG table computation (exact port of reference) ----

static double fct(int n) { double r = 1.0; for (int i = 2; i <= n; ++i) r *= i; return r; }

static double su2_cg_coeff(int j1, int m1, int j2, int m2, int j3, int m3) {
    if (m3 != m1 + m2) return 0.0;
    int vmin = std::max(std::max(-j1 + j2 + m3, -j1 + m1), 0);
    int vmax = std::min(std::min(j2 + j3 + m1, j3 - j1 + j2), j3 + m3);
    double C = std::sqrt((2.0 * j3 + 1.0) * fct(j3 + j1 - j2) * fct(j3 - j1 + j2) * fct(j1 + j2 - j3)
                         * fct(j3 + m3) * fct(j3 - m3)
                         / (fct(j1 + j2 + j3 + 1) * fct(j1 - m1) * fct(j1 + m1) * fct(j2 - m2) * fct(j2 + m2)));
    double S = 0.0;
    for (int v = vmin; v <= vmax; ++v) {
        double sgn = ((v + j2 + m2) & 1) ? -1.0 : 1.0;
        S += sgn * fct(j2 + j3 + m1 - v) * fct(j1 - m1 + v)
             / (fct(v) * fct(j3 - j1 + j2 - v) * fct(j3 + m3 - v) * fct(v + j1 - j2 - m3));
    }
    return C * S;
}

// change-of-basis real->complex, rows = complex index (l+m), cols = real index
static void cob(int l, std::complex<double> q[5][5]) {
    for (int a = 0; a < 5; ++a) for (int b = 0; b < 5; ++b) q[a][b] = 0.0;
    const double is2 = 1.0 / std::sqrt(2.0);
    for (int m = -l; m < 0; ++m) {
        q[l + m][l - m] = is2;
        q[l + m][l + m] = std::complex<double>(0.0, -is2);
    }
    q[l][l] = 1.0;
    for (int m = 1; m <= l; ++m) {
        double sgn = (m & 1) ? -1.0 : 1.0;
        q[l + m][l + m] = sgn * is2;
        q[l + m][l - m] = std::complex<double>(0.0, sgn * is2);
    }
    std::complex<double> ph;
    switch (l & 3) {
        case 0: ph = 1.0; break;
        case 1: ph = std::complex<double>(0.0, -1.0); break;
        case 2: ph = -1.0; break;
        default: ph = std::complex<double>(0.0, 1.0); break;
    }
    for (int a = 0; a < 5; ++a) for (int b = 0; b < 5; ++b) q[a][b] *= ph;
}

// real-basis wigner 3j, normalized to unit Frobenius norm. out is d1*d2*d3 row-major [j][l][m].
static void wigner3j(int l1, int l2, int l3, double* out) {
    int d1 = 2 * l1 + 1, d2 = 2 * l2 + 1, d3 = 2 * l3 + 1;
    double csu2[5][5][5] = {};
    for (int m1 = -l1; m1 <= l1; ++m1)
        for (int m2 = -l2; m2 <= l2; ++m2)
            if (std::abs(m1 + m2) <= l3)
                csu2[l1 + m1][l2 + m2][l3 + m1 + m2] =
                    su2_cg_coeff(l1, m1, l2, m2, l3, m1 + m2) / std::sqrt(2.0 * l3 + 1.0);
    std::complex<double> Q1[5][5], Q2[5][5], Q3[5][5];
    cob(l1, Q1); cob(l2, Q2); cob(l3, Q3);
    double nrm = 0.0;
    for (int j = 0; j < d1; ++j)
        for (int l = 0; l < d2; ++l)
            for (int m = 0; m < d3; ++m) {
                std::complex<double> s = 0.0;
                for (int i = 0; i < d1; ++i)
                    for (int k = 0; k < d2; ++k)
                        for (int n = 0; n < d3; ++n)
                            s += Q1[i][j] * Q2[k][l] * std::conj(Q3[n][m]) * csu2[i][k][n];
                out[(j * d2 + l) * d3 + m] = s.real();
                nrm += s.real() * s.real();
            }
    nrm = std::sqrt(nrm);
    for (int t = 0; t < d1 * d2 * d3; ++t) out[t] /= nrm;
}

struct CGTab {
    float cA;        // 0x0->0 scalar coefficient
    float B[9];      // 1x1->0 : [i*3+j]
    float Cjk[9];    // 0x1->1 : [j*3+k]
    float Dik[9];    // 1x0->1 : [i*3+k]
    float E[27];     // 1x1->1 : [(i*3+j)*3+k]
    float F[45];     // 1x1->2 : [(i*3+j)*5+k]
};

// ---------------- device kernel ---------------------------------------------
// R5: single-pass rows. 512 threads/block, one block == one output row, no
// h-loop. Rationale: loads and stores share vmcnt on CDNA; R4's h=1 loads
// forced each wave to drain its h=0 store queue (s_waitcnt vmcnt(N) counts
// stores) -> exposed store-ack latency under saturated write BW. Here a wave
// issues ALL its loads before ANY store, so no store drain is ever on the
// critical path; stores retire during wave teardown while new blocks launch.
//
// Layout facts (mul1*mul2 == n == 2048), verified against reference reshapes:
//   out[r, c], r = u*32 + v; chunk col = chunk_base + nn*d3 + k3
//   x1_l0[u,nn]   = in1[(u*32 + nn/64)*256 + (nn%64)]
//   x1_l1[i,u,nn] = in1[(f/192)*256 + 64 + f%192],  f = i*131072 + u*2048 + nn
//   x2_l0[v,nn]   = in2[(v*64 + nn/32)*128 + (nn%32)]
//   x2_l1[j,v,nn] = in2[(g/96)*128 + 32 + g%96],    g = j*65536 + v*2048 + nn
// nn = 4*t (t in [0,512)): every operand quad is contiguous + 16B aligned
// (the /192, /96 row wraps land on multiples of 4) -> all loads are float4.
//
// Stores: A,B (d3=1) are naturally unit-stride -> direct dwordx4.
// C/D/E/F bounce through 5KB wave-local LDS scratch (write lane-stride
// 48B/80B - both are the baseline b128 bank pattern, conflict-free; read
// unit-stride) then store unit-stride 1KB-per-instruction bursts. DS ops are
// wave-in-order: lgkmcnt(0) + sched_barrier is the only sync. No
// __syncthreads in the kernel.
//
// Sorted chunk bases in float4 units within a row (row = 8192 float4s):
//   A:0  B:512  C:1024  D:2560  E:4096  F:5632

__global__ __launch_bounds__(512) void ftp_kernel(const float* __restrict__ in1,
                                                  const float* __restrict__ in2,
                                                  float* __restrict__ out,
                                                  CGTab cg) {
    __shared__ float lds[8][1280];   // 40 KB: 5 KB wave-local scratch x 8 waves

    const int t    = threadIdx.x;    // 0..511
    const int w    = t >> 6;
    const int lane = t & 63;
    const int r    = blockIdx.x;     // 0..2047
    const int u    = r >> 5;
    const int v    = r & 31;
    float4* __restrict__ orow4 = (float4*)(out + (size_t)r * 32768);
    float* ldsW = lds[w];
    const float4* ldsW4 = (const float4*)ldsW;

    const int nn  = t * 4;           // quad base, 0..2044
    const int q4w = w * 64;          // wave's nn base in float4 units

    alignas(16) float a0q[4], b0q[4], a1q[3][4], b1q[3][4];
    *(float4*)a0q = *(const float4*)&in1[(u * 32 + (nn >> 6)) * 256 + (nn & 63)];
    *(float4*)b0q = *(const float4*)&in2[(v * 64 + (nn >> 5)) * 128 + (nn & 31)];
#pragma unroll
    for (int i = 0; i < 3; ++i) {
        const int f   = i * 131072 + u * 2048 + nn;
        const int row = f / 192, col = f - row * 192;
        *(float4*)a1q[i] = *(const float4*)&in1[row * 256 + 64 + col];
    }
#pragma unroll
    for (int j = 0; j < 3; ++j) {
        const int g   = j * 65536 + v * 2048 + nn;
        const int row = g / 96, col = g - row * 96;
        *(float4*)b1q[j] = *(const float4*)&in2[row * 128 + 32 + col];
    }

    // ---- A: 0e from 0x0 (unit-stride, direct) ----
    {
        alignas(16) float o[4];
#pragma unroll
        for (int d = 0; d < 4; ++d) o[d] = cg.cA * a0q[d] * b0q[d];
        orow4[t] = *(const float4*)o;
    }

    // ---- B: 0e from 1x1 (unit-stride, direct) ----
    {
        alignas(16) float o[4];
#pragma unroll
        for (int d = 0; d < 4; ++d) {
            float s = 0.f;
#pragma unroll
            for (int i = 0; i < 3; ++i)
#pragma unroll
                for (int j = 0; j < 3; ++j)
                    s = fmaf(cg.B[i * 3 + j], a1q[i][d] * b1q[j][d], s);
            o[d] = s;
        }
        orow4[512 + t] = *(const float4*)o;
    }

    alignas(16) float o[20];

    // helper: stage o[0..4*D3) through wave-local LDS, emit D3 coalesced stores
    auto bounce = [&](auto d3c, float4* dst) {
        constexpr int D3 = decltype(d3c)::value;
#pragma unroll
        for (int s = 0; s < D3; ++s)
            *(float4*)&ldsW[lane * 4 * D3 + 4 * s] = *(const float4*)&o[4 * s];
        __builtin_amdgcn_wave_barrier();
        asm volatile("s_waitcnt lgkmcnt(0)" ::: "memory");
        __builtin_amdgcn_sched_barrier(0);
#pragma unroll
        for (int s = 0; s < D3; ++s)
            dst[lane + 64 * s] = ldsW4[lane + 64 * s];
        __builtin_amdgcn_wave_barrier();
    };

    // ---- C: 1o from 0x1 ----
#pragma unroll
    for (int d = 0; d < 4; ++d)
#pragma unroll
        for (int k = 0; k < 3; ++k) {
            float s = 0.f;
#pragma unroll
            for (int j = 0; j < 3; ++j) s = fmaf(cg.Cjk[j * 3 + k], b1q[j][d], s);
            o[d * 3 + k] = a0q[d] * s;
        }
    bounce(std::integral_constant<int, 3>{}, orow4 + 1024 + 3 * q4w);

    // ---- D: 1o from 1x0 ----
#pragma unroll
    for (int d = 0; d < 4; ++d)
#pragma unroll
        for (int k = 0; k < 3; ++k) {
            float s = 0.f;
#pragma unroll
            for (int i = 0; i < 3; ++i) s = fmaf(cg.Dik[i * 3 + k], a1q[i][d], s);
            o[d * 3 + k] = b0q[d] * s;
        }
    bounce(std::integral_constant<int, 3>{}, orow4 + 2560 + 3 * q4w);

    // ---- E: 1e from 1x1 ----
#pragma unroll
    for (int d = 0; d < 4; ++d)
#pragma unroll
        for (int k = 0; k < 3; ++k) {
            float s = 0.f;
#pragma unroll
            for (int i = 0; i < 3; ++i)
#pragma unroll
                for (int j = 0; j < 3; ++j)
                    s = fmaf(cg.E[(i * 3 + j) * 3 + k], a1q[i][d] * b1q[j][d], s);
            o[d * 3 + k] = s;
        }
    bounce(std::integral_constant<int, 3>{}, orow4 + 4096 + 3 * q4w);

    // ---- F: 2e from 1x1 ----
#pragma unroll
    for (int d = 0; d < 4; ++d)
#pragma unroll
        for (int k = 0; k < 5; ++k) {
            float s = 0.f;
#pragma unroll
            for (int i = 0; i < 3; ++i)
#pragma unroll
                for (int j = 0; j < 3; ++j)
                    s = fmaf(cg.F[(i * 3 + j) * 5 + k], a1q[i][d] * b1q[j][d], s);
            o[d * 5 + k] = s;
        }
    bounce(std::integral_constant<int, 5>{}, orow4 + 5632 + 5 * q4w);
}

// ---------------- launch ------------------------------------------------------

extern "C" void kernel_launch(void* const* d_in, const int* in_sizes, int n_in,
                              void* d_out, int out_size, void* d_ws, size_t ws_size,
                              hipStream_t stream) {
    const float* in1 = (const float*)d_in[0];  // (2048, 256) fp32
    const float* in2 = (const float*)d_in[1];  // (2048, 128) fp32
    float* out = (float*)d_out;                // (2048, 32768) fp32

    // Host-side CG tables (pure CPU math — graph-capture safe; passed by value).
    CGTab cg;
    double w[45];
    const double s3 = std::sqrt(3.0), s5 = std::sqrt(5.0);

    wigner3j(0, 0, 0, w);
    cg.cA = (float)(w[0] * 1.0);

    wigner3j(1, 1, 0, w);  // [i][j][0]
    for (int i = 0; i < 3; ++i)
        for (int j = 0; j < 3; ++j) cg.B[i * 3 + j] = (float)(w[(i * 3 + j)] * 1.0);

    wigner3j(0, 1, 1, w);  // [0][j][k]
    for (int j = 0; j < 3; ++j)
        for (int k = 0; k < 3; ++k) cg.Cjk[j * 3 + k] = (float)(w[j * 3 + k] * s3);

    wigner3j(1, 0, 1, w);  // [i][0][k]
    for (int i = 0; i < 3; ++i)
        for (int k = 0; k < 3; ++k) cg.Dik[i * 3 + k] = (float)(w[i * 3 + k] * s3);

    wigner3j(1, 1, 1, w);  // [i][j][k]
    for (int t = 0; t < 27; ++t) cg.E[t] = (float)(w[t] * s3);

    wigner3j(1, 1, 2, w);  // [i][j][k], d3 = 5
    for (int t = 0; t < 45; ++t) cg.F[t] = (float)(w[t] * s5);

    dim3 grid(2048, 1, 1);
    dim3 block(512, 1, 1);
    ftp_kernel<<<grid, block, 0, stream>>>(in1, in2, out, cg);
}